// Round 1
// baseline (231.338 us; speedup 1.0000x reference)
//
#include <hip/hip_runtime.h>
#include <stdint.h>
#include <stddef.h>

// ---- problem constants ----
#define K_CODES 1024
#define D_DIM   256
#define HW      1024      // 32*32 spatial
#define B_BATCH 32
#define N_VEC   32768     // B*HW
#define TOT_ELEMS 8388608 // N_VEC * D_DIM

typedef float    v4f __attribute__((ext_vector_type(4)));
typedef _Float16 v8h __attribute__((ext_vector_type(8)));

// ------------------------------------------------------------------
// K1: codebook -> fp16 copy + per-code squared norm
// grid: K_CODES blocks x 256 threads (one thread per d)
__global__ void prep_emb(const float* __restrict__ emb,
                         _Float16* __restrict__ emb_h,
                         float* __restrict__ norm_e) {
    int k = blockIdx.x;
    int t = threadIdx.x;
    float v = emb[(size_t)k * D_DIM + t];
    emb_h[(size_t)k * D_DIM + t] = (_Float16)v;
    float s = v * v;
    for (int off = 32; off; off >>= 1) s += __shfl_down(s, off);
    __shared__ float wsum[4];
    if ((t & 63) == 0) wsum[t >> 6] = s;
    __syncthreads();
    if (t == 0) norm_e[k] = wsum[0] + wsum[1] + wsum[2] + wsum[3];
}

// ------------------------------------------------------------------
// K2: transpose z [B][D][HW] fp32 -> zt [B*HW][D] fp16
// grid: 32 b * 16 mchunk * 4 dchunk = 2048 blocks, 256 threads
__global__ void transpose_z(const float* __restrict__ z,
                            _Float16* __restrict__ zt) {
    int blk = blockIdx.x;
    int b   = blk >> 6;
    int rem = blk & 63;
    int m0  = (rem >> 2) * 64;
    int d0  = (rem & 3) * 64;
    __shared__ float tile[64][65];   // [d][m], pad -> conflict-free
    int t  = threadIdx.x;
    int ml = t & 63;
    int dl = t >> 6;                 // 0..3
    const float* zb = z + (size_t)b * D_DIM * HW;
#pragma unroll
    for (int p = 0; p < 16; ++p) {
        int d = d0 + dl + p * 4;
        tile[dl + p * 4][ml] = zb[(size_t)d * HW + m0 + ml];
    }
    __syncthreads();
    int dl2 = t & 63;
    int ml2 = t >> 6;
#pragma unroll
    for (int p = 0; p < 16; ++p) {
        int m = ml2 + p * 4;
        zt[(size_t)(b * HW + m0 + m) * D_DIM + d0 + dl2] =
            (_Float16)tile[dl2][m];
    }
}

// ------------------------------------------------------------------
// K3: fused distance GEMM (fp16 MFMA) + argmin over K codes
// grid: N_VEC/64 = 512 blocks, 256 threads (4 waves x 16 rows each)
// dist(m,k) = -2 * <z_m, e_k> + ||e_k||^2   (||z||^2 dropped: row-const)
__global__ __launch_bounds__(256) void
argmin_codes(const _Float16* __restrict__ zt,
             const _Float16* __restrict__ emb_h,
             const float* __restrict__ norm_e,
             int* __restrict__ idx_buf) {
    __shared__ float norm_s[K_CODES];
    int t = threadIdx.x;
#pragma unroll
    for (int i = 0; i < 4; ++i) norm_s[t + i * 256] = norm_e[t + i * 256];
    __syncthreads();

    int wave = t >> 6;
    int lane = t & 63;
    int col  = lane & 15;   // A row within tile / code col within chunk
    int quad = lane >> 4;
    int m0   = blockIdx.x * 64 + wave * 16;

    // A fragments: 8 K-chunks of 32 (full D=256), resident in regs
    v8h af[8];
    {
        const v8h* p = reinterpret_cast<const v8h*>(
            zt + (size_t)(m0 + col) * D_DIM) + quad;
#pragma unroll
        for (int c = 0; c < 8; ++c) af[c] = p[c * 4];
    }

    float minv[4] = {3.4e38f, 3.4e38f, 3.4e38f, 3.4e38f};
    int   mini[4] = {0, 0, 0, 0};

    // 32 iterations, 2 code-chunks (16 codes each) per iter for MFMA ILP
    for (int kt = 0; kt < 32; ++kt) {
        int k0 = kt * 32 + col;
        int k1 = k0 + 16;
        const v8h* q0 = reinterpret_cast<const v8h*>(
            emb_h + (size_t)k0 * D_DIM) + quad;
        const v8h* q1 = reinterpret_cast<const v8h*>(
            emb_h + (size_t)k1 * D_DIM) + quad;
        v4f acc0 = {0.f, 0.f, 0.f, 0.f};
        v4f acc1 = {0.f, 0.f, 0.f, 0.f};
#pragma unroll
        for (int c = 0; c < 8; ++c) {
            v8h b0 = q0[c * 4];
            v8h b1 = q1[c * 4];
            acc0 = __builtin_amdgcn_mfma_f32_16x16x32_f16(af[c], b0, acc0, 0, 0, 0);
            acc1 = __builtin_amdgcn_mfma_f32_16x16x32_f16(af[c], b1, acc1, 0, 0, 0);
        }
        float n0 = norm_s[k0];
        float n1 = norm_s[k1];
#pragma unroll
        for (int r = 0; r < 4; ++r) {
            float d0 = fmaf(-2.f, acc0[r], n0);
            if (d0 < minv[r]) { minv[r] = d0; mini[r] = k0; }
            float d1 = fmaf(-2.f, acc1[r], n1);
            if (d1 < minv[r]) { minv[r] = d1; mini[r] = k1; }
        }
    }
    // reduce across the 16 lanes of each quad (cols of the chunk)
#pragma unroll
    for (int off = 1; off < 16; off <<= 1) {
#pragma unroll
        for (int r = 0; r < 4; ++r) {
            float ov = __shfl_xor(minv[r], off);
            int   oi = __shfl_xor(mini[r], off);
            if (ov < minv[r] || (ov == minv[r] && oi < mini[r])) {
                minv[r] = ov; mini[r] = oi;
            }
        }
    }
    if (col == 0) {
#pragma unroll
        for (int r = 0; r < 4; ++r)
            idx_buf[m0 + quad * 4 + r] = mini[r];
    }
}

// ------------------------------------------------------------------
// K4: gather z_q = emb[idx], write output, fused loss accumulation
// grid: 1024 blocks (32 spatial positions each), 256 threads
__global__ void gather_out(const float* __restrict__ z,
                           const float* __restrict__ emb,
                           const int* __restrict__ idx_buf,
                           float* __restrict__ out,
                           float* __restrict__ loss_acc) {
    int blk = blockIdx.x;
    int b   = blk >> 5;
    int sp0 = (blk & 31) * 32;
    int t   = threadIdx.x;
    __shared__ int   idx_s[32];
    __shared__ float zq[32][257];   // [pos][d], pad -> conflict-free
    if (t < 32) idx_s[t] = idx_buf[b * HW + sp0 + t];
    __syncthreads();
#pragma unroll 4
    for (int i = 0; i < 32; ++i) {
        zq[i][t] = emb[(size_t)idx_s[i] * D_DIM + t];
    }
    __syncthreads();
    int j  = t & 31;   // spatial within chunk
    int dq = t >> 5;   // 0..7
    float sum = 0.f;
#pragma unroll
    for (int p = 0; p < 32; ++p) {
        int d = dq * 32 + p;
        size_t o = (size_t)(b * D_DIM + d) * HW + sp0 + j;
        float q  = zq[j][d];
        float e  = z[o];
        float df = q - e;
        sum += df * df;
        out[o] = q;    // z_q_st == z_q numerically
    }
    for (int off = 32; off; off >>= 1) sum += __shfl_down(sum, off);
    __shared__ float wsum[4];
    if ((t & 63) == 0) wsum[t >> 6] = sum;
    __syncthreads();
    if (t == 0) atomicAdd(loss_acc, wsum[0] + wsum[1] + wsum[2] + wsum[3]);
}

// ------------------------------------------------------------------
// K5: vq_loss = (1 + BETA) * mean  = 1.25 * sum / TOT_ELEMS
__global__ void finalize(const float* __restrict__ loss_acc,
                         float* __restrict__ out_loss) {
    out_loss[0] = loss_acc[0] * (1.25f / (float)TOT_ELEMS);
}

// ------------------------------------------------------------------
extern "C" void kernel_launch(void* const* d_in, const int* in_sizes, int n_in,
                              void* d_out, int out_size, void* d_ws, size_t ws_size,
                              hipStream_t stream) {
    const float* z   = (const float*)d_in[0];   // [32,256,32,32]
    const float* emb = (const float*)d_in[1];   // [1024,256]
    float* out = (float*)d_out;                 // [8388608 z_q_st][1 loss]

    char* ws = (char*)d_ws;
    float*     loss_acc = (float*)ws;                              // 4 B
    float*     norm_e   = (float*)(ws + 1024);                     // 4 KB
    _Float16*  emb_h    = (_Float16*)(ws + 8192);                  // 512 KB
    _Float16*  zt       = (_Float16*)(ws + (1 << 20));             // 16 MB
    int*       idx_buf  = (int*)(ws + (1 << 20) + (16 << 20));     // 128 KB

    hipMemsetAsync(d_ws, 0, 256, stream);
    prep_emb<<<dim3(K_CODES), dim3(256), 0, stream>>>(emb, emb_h, norm_e);
    transpose_z<<<dim3(2048), dim3(256), 0, stream>>>(z, zt);
    argmin_codes<<<dim3(N_VEC / 64), dim3(256), 0, stream>>>(zt, emb_h, norm_e, idx_buf);
    gather_out<<<dim3(1024), dim3(256), 0, stream>>>(z, emb, idx_buf, out, loss_acc);
    finalize<<<dim3(1), dim3(1), 0, stream>>>(loss_acc, out + TOT_ELEMS);
}

// Round 2
// 147.850 us; speedup vs baseline: 1.5647x; 1.5647x over previous
//
#include <hip/hip_runtime.h>
#include <stdint.h>
#include <stddef.h>

// ---- problem constants ----
#define K_CODES 1024
#define D_DIM   256
#define HW      1024      // 32*32 spatial
#define N_VEC   32768     // B*HW
#define TOT_ELEMS 8388608 // N_VEC * D_DIM

typedef float    v4f __attribute__((ext_vector_type(4)));
typedef _Float16 v8h __attribute__((ext_vector_type(8)));
typedef _Float16 v2h __attribute__((ext_vector_type(2)));

// async global->LDS, 16B per lane, dest = wave-uniform base + lane*16
__device__ __forceinline__ void gld_lds16(const void* g, void* l) {
    __builtin_amdgcn_global_load_lds(
        (const __attribute__((address_space(1))) void*)g,
        (__attribute__((address_space(3))) void*)l, 16, 0, 0);
}

// ------------------------------------------------------------------
// K1: codebook -> fp16 copy + 0.5*||e||^2
__global__ void prep_emb(const float* __restrict__ emb,
                         _Float16* __restrict__ emb_h,
                         float* __restrict__ hnorm) {
    int k = blockIdx.x;
    int t = threadIdx.x;
    float v = emb[(size_t)k * D_DIM + t];
    emb_h[(size_t)k * D_DIM + t] = (_Float16)v;
    float s = v * v;
    for (int off = 32; off; off >>= 1) s += __shfl_down(s, off);
    __shared__ float wsum[4];
    if ((t & 63) == 0) wsum[t >> 6] = s;
    __syncthreads();
    if (t == 0) hnorm[k] = 0.5f * (wsum[0] + wsum[1] + wsum[2] + wsum[3]);
}

// ------------------------------------------------------------------
// K2: transpose z [B][D][HW] fp32 -> zt [B*HW][D] fp16
__global__ void transpose_z(const float* __restrict__ z,
                            _Float16* __restrict__ zt) {
    int blk = blockIdx.x;
    int b   = blk >> 6;
    int rem = blk & 63;
    int m0  = (rem >> 2) * 64;
    int d0  = (rem & 3) * 64;
    __shared__ float tile[64][65];   // [d][m]
    int t  = threadIdx.x;
    int ml = t & 63;
    int dl = t >> 6;                 // 0..3
    const float* zb = z + (size_t)b * D_DIM * HW;
#pragma unroll
    for (int p = 0; p < 16; ++p) {
        int d = dl + p * 4;
        tile[d][ml] = zb[(size_t)(d0 + d) * HW + m0 + ml];
    }
    __syncthreads();
    int dp = t & 31;   // d-pair 0..31
    int mb = t >> 5;   // 0..7
#pragma unroll
    for (int p = 0; p < 8; ++p) {
        int m = p * 8 + mb;
        v2h u = { (_Float16)tile[2 * dp][m], (_Float16)tile[2 * dp + 1][m] };
        *(v2h*)(zt + (size_t)(b * HW + m0 + m) * D_DIM + d0 + 2 * dp) = u;
    }
}

// ------------------------------------------------------------------
// K3: fused distance GEMM (fp16 MFMA, LDS-staged B) + argmin, K-split x2
// grid: 512 blocks (h = blk&1 K-half, rb = blk>>1), 256 threads,
// 4 waves x 32 rows = 128 rows/block.
// dist' = 0.5*||e||^2 - <z,e>  (argmin-equivalent)
__global__ __launch_bounds__(256, 2) void
argmin_codes(const _Float16* __restrict__ zt,
             const _Float16* __restrict__ emb_h,
             const float* __restrict__ hnorm,
             float* __restrict__ part) {
    __shared__ __align__(16) _Float16 btile[2][64 * D_DIM];   // 2 x 32 KB

    int t    = threadIdx.x;
    int wave = t >> 6;
    int lane = t & 63;
    int col  = lane & 15;
    int quad = lane >> 4;

    int h  = blockIdx.x & 1;
    int rb = blockIdx.x >> 1;
    int m0 = rb * 128 + wave * 32;
    const _Float16* eh = emb_h + (size_t)h * 512 * D_DIM;
    const float*    nh = hnorm + h * 512;

    // A fragments: 2 row-tiles x 8 D-chunks, resident
    v8h af0[8], af1[8];
    {
        const v8h* p0 = (const v8h*)(zt + (size_t)(m0 + col) * D_DIM);
        const v8h* p1 = (const v8h*)(zt + (size_t)(m0 + 16 + col) * D_DIM);
#pragma unroll
        for (int c = 0; c < 8; ++c) {
            af0[c] = p0[quad + c * 4];
            af1[c] = p1[quad + c * 4];
        }
    }
    // half-norms for my col: nrm[T*4+cc] = nh[(T*4+cc)*16 + col]
    float nrm[32];
#pragma unroll
    for (int i = 0; i < 32; ++i) nrm[i] = nh[i * 16 + col];

    // stage tile T (64 codes, 32 KB) into buffer buf with XOR-16B swizzle:
    // logical (code k, granule g) -> phys k*512 + ((g+k)&31)*16
    auto stage = [&](int buf, int T) {
        const char* src_base = (const char*)(eh + (size_t)T * 64 * D_DIM);
        char* dst_base = (char*)&btile[buf][0] + wave * 1024;
#pragma unroll
        for (int i = 0; i < 8; ++i) {
            int k = i * 8 + (t >> 5);
            int g = ((t & 31) - k) & 31;
            gld_lds16(src_base + k * 512 + g * 16, dst_base + i * 4096);
        }
    };

    float minv[8];
    int   mini[8];
#pragma unroll
    for (int r = 0; r < 8; ++r) { minv[r] = 3.4e38f; mini[r] = 0; }

    stage(0, 0);
    for (int T = 0; T < 8; ++T) {
        __syncthreads();                    // buf[T&1] staged (vmcnt drained)
        if (T < 7) stage((T + 1) & 1, T + 1);
        const _Float16* bt = &btile[T & 1][0];
#pragma unroll
        for (int cc = 0; cc < 4; ++cc) {
            int k = cc * 16 + col;          // code within tile
            v8h bf[8];
#pragma unroll
            for (int c = 0; c < 8; ++c) {
                int g = c * 4 + quad;
                bf[c] = *(const v8h*)(bt + k * D_DIM + (((g + k) & 31) << 3));
            }
            v4f acc0 = {0.f, 0.f, 0.f, 0.f};
            v4f acc1 = {0.f, 0.f, 0.f, 0.f};
#pragma unroll
            for (int c = 0; c < 8; ++c) {
                acc0 = __builtin_amdgcn_mfma_f32_16x16x32_f16(af0[c], bf[c], acc0, 0, 0, 0);
                acc1 = __builtin_amdgcn_mfma_f32_16x16x32_f16(af1[c], bf[c], acc1, 0, 0, 0);
            }
            float n   = nrm[T * 4 + cc];
            int  code = T * 64 + k;         // within half
#pragma unroll
            for (int r = 0; r < 4; ++r) {
                float d0 = n - acc0[r];
                if (d0 < minv[r])     { minv[r]     = d0; mini[r]     = code; }
                float d1 = n - acc1[r];
                if (d1 < minv[4 + r]) { minv[4 + r] = d1; mini[4 + r] = code; }
            }
        }
    }
    // reduce across the 16 cols of each quad
#pragma unroll
    for (int off = 1; off < 16; off <<= 1) {
#pragma unroll
        for (int r = 0; r < 8; ++r) {
            float ov = __shfl_xor(minv[r], off);
            int   oi = __shfl_xor(mini[r], off);
            if (ov < minv[r] || (ov == minv[r] && oi < mini[r])) {
                minv[r] = ov; mini[r] = oi;
            }
        }
    }
    if (col == 0) {
#pragma unroll
        for (int r = 0; r < 8; ++r) {
            int row = m0 + (r >> 2) * 16 + quad * 4 + (r & 3);
            float2 v;
            v.x = minv[r];
            v.y = __int_as_float(mini[r] + h * 512);   // global code idx
            *(float2*)(part + ((size_t)h * N_VEC + row) * 2) = v;
        }
    }
}

// ------------------------------------------------------------------
// K4: merge K-split argmin, gather z_q = emb[idx], write out, fused loss
__global__ void gather_out(const float* __restrict__ z,
                           const float* __restrict__ emb,
                           const float* __restrict__ part,
                           float* __restrict__ out,
                           float* __restrict__ loss_acc) {
    int blk = blockIdx.x;
    int b   = blk >> 5;
    int sp0 = (blk & 31) * 32;
    int t   = threadIdx.x;
    __shared__ int   idx_s[32];
    __shared__ float zq[32][257];
    if (t < 32) {
        int row = b * HW + sp0 + t;
        float2 p0 = *(const float2*)(part + (size_t)row * 2);
        float2 p1 = *(const float2*)(part + (size_t)(N_VEC + row) * 2);
        // strict <: ties prefer half 0 (lower idx), matching argmin-first
        idx_s[t] = (p1.x < p0.x) ? __float_as_int(p1.y) : __float_as_int(p0.y);
    }
    __syncthreads();
#pragma unroll 4
    for (int i = 0; i < 32; ++i) {
        zq[i][t] = emb[(size_t)idx_s[i] * D_DIM + t];
    }
    __syncthreads();
    int j  = t & 31;
    int dq = t >> 5;
    float sum = 0.f;
#pragma unroll
    for (int p = 0; p < 32; ++p) {
        int d = dq * 32 + p;
        size_t o = (size_t)(b * D_DIM + d) * HW + sp0 + j;
        float q  = zq[j][d];
        float e  = z[o];
        float df = q - e;
        sum += df * df;
        out[o] = q;                 // z_q_st == z_q numerically
    }
    for (int off = 32; off; off >>= 1) sum += __shfl_down(sum, off);
    __shared__ float wsum[4];
    if ((t & 63) == 0) wsum[t >> 6] = sum;
    __syncthreads();
    if (t == 0) atomicAdd(loss_acc, wsum[0] + wsum[1] + wsum[2] + wsum[3]);
}

// ------------------------------------------------------------------
// K5: vq_loss = 1.25 * sum / TOT_ELEMS
__global__ void finalize(const float* __restrict__ loss_acc,
                         float* __restrict__ out_loss) {
    out_loss[0] = loss_acc[0] * (1.25f / (float)TOT_ELEMS);
}

// ------------------------------------------------------------------
extern "C" void kernel_launch(void* const* d_in, const int* in_sizes, int n_in,
                              void* d_out, int out_size, void* d_ws, size_t ws_size,
                              hipStream_t stream) {
    const float* z   = (const float*)d_in[0];   // [32,256,32,32]
    const float* emb = (const float*)d_in[1];   // [1024,256]
    float* out = (float*)d_out;                 // [8388608 z_q_st][1 loss]

    char* ws = (char*)d_ws;
    float*     loss_acc = (float*)ws;                        // @0
    float*     hnorm    = (float*)(ws + 1024);               // 4 KB
    float*     part     = (float*)(ws + 8192);               // 512 KB
    _Float16*  emb_h    = (_Float16*)(ws + 8192 + 524288);   // 512 KB
    _Float16*  zt       = (_Float16*)(ws + 8192 + 1048576);  // 16 MB

    hipMemsetAsync(d_ws, 0, 256, stream);
    prep_emb<<<dim3(K_CODES), dim3(256), 0, stream>>>(emb, emb_h, hnorm);
    transpose_z<<<dim3(2048), dim3(256), 0, stream>>>(z, zt);
    argmin_codes<<<dim3(512), dim3(256), 0, stream>>>(zt, emb_h, hnorm, part);
    gather_out<<<dim3(1024), dim3(256), 0, stream>>>(z, emb, part, out, loss_acc);
    finalize<<<dim3(1), dim3(1), 0, stream>>>(loss_acc, out + TOT_ELEMS);
}

// Round 3
// 135.641 us; speedup vs baseline: 1.7055x; 1.0900x over previous
//
#include <hip/hip_runtime.h>
#include <stdint.h>
#include <stddef.h>

// ---- problem constants ----
#define K_CODES 1024
#define D_DIM   256
#define HW      1024      // 32*32 spatial
#define N_VEC   32768
#define TOT_ELEMS 8388608

typedef float    v4f __attribute__((ext_vector_type(4)));
typedef _Float16 v8h __attribute__((ext_vector_type(8)));

// async global->LDS, 16B/lane, dest = wave-uniform base + lane*16
__device__ __forceinline__ void gld_lds16(const void* g, void* l) {
    __builtin_amdgcn_global_load_lds(
        (const __attribute__((address_space(1))) void*)g,
        (__attribute__((address_space(3))) void*)l, 16, 0, 0);
}

// ------------------------------------------------------------------
// K1: codebook -> fp16 copy + 0.5*||e||^2
__global__ void prep_emb(const float* __restrict__ emb,
                         _Float16* __restrict__ emb_h,
                         float* __restrict__ hnorm) {
    int k = blockIdx.x, t = threadIdx.x;
    float v = emb[(size_t)k * D_DIM + t];
    emb_h[(size_t)k * D_DIM + t] = (_Float16)v;
    float s = v * v;
    for (int off = 32; off; off >>= 1) s += __shfl_down(s, off);
    __shared__ float wsum[4];
    if ((t & 63) == 0) wsum[t >> 6] = s;
    __syncthreads();
    if (t == 0) hnorm[k] = 0.5f * (wsum[0] + wsum[1] + wsum[2] + wsum[3]);
}

// ------------------------------------------------------------------
// K2: fully fused VQ: load z (strided) -> MFMA distance vs LDS-staged
// codebook -> argmin -> gather emb (L2) -> write out + loss partial.
// grid: 256 blocks (1/CU), 256 thr = 4 waves x 32 rows; full K per block.
// dist' = 0.5*||e||^2 - <z,e>  (argmin-equivalent)
__global__ __launch_bounds__(256, 1) void
vq_main(const float* __restrict__ z,
        const _Float16* __restrict__ emb_h,
        const float* __restrict__ emb,
        const float* __restrict__ hnorm,
        float* __restrict__ out,
        float* __restrict__ loss_acc) {
    __shared__ __align__(16) _Float16 btile[2][64 * D_DIM];   // 2 x 32 KB
    __shared__ float norm_s[K_CODES];
    __shared__ int   idx_s[128];
    __shared__ float wred[4];

    int t    = threadIdx.x;
    int wave = t >> 6;
    int lane = t & 63;
    int col  = lane & 15;
    int quad = lane >> 4;
    int b    = blockIdx.x >> 3;
    int hw0  = (blockIdx.x & 7) * 128;
    const float* zb = z + (size_t)b * D_DIM * HW;

    // stage code-tile T (64 codes, 32 KB) with XOR-16B swizzle:
    // logical (code k, granule g) -> phys slot u = g ^ ((k&7)<<2)
    auto stage = [&](int buf, int T) {
        const char* src = (const char*)(emb_h + (size_t)T * 64 * D_DIM);
        char* dst = (char*)&btile[buf][0] + wave * 8192;
#pragma unroll
        for (int i = 0; i < 8; ++i) {
            int k = wave * 16 + i * 2 + (lane >> 5);
            int u = lane & 31;
            int g = u ^ ((k & 7) << 2);
            gld_lds16(src + (size_t)k * 512 + (size_t)g * 16, dst + i * 1024);
        }
    };
    stage(0, 0);   // overlap first staging with prologue

    for (int i = t; i < K_CODES; i += 256) norm_s[i] = hnorm[i];

    // A fragments (2 row-tiles x 8 D-chunks) straight from z, fp32->fp16
    int m0w = hw0 + wave * 32;
    v8h af0[8], af1[8];
#pragma unroll
    for (int c = 0; c < 8; ++c) {
#pragma unroll
        for (int j = 0; j < 8; ++j) {
            int d = c * 32 + quad * 8 + j;
            const float* p = zb + (size_t)d * HW + m0w + col;
            af0[c][j] = (_Float16)p[0];
            af1[c][j] = (_Float16)p[16];
        }
    }

    float minv[8]; int mini[8];
#pragma unroll
    for (int r = 0; r < 8; ++r) { minv[r] = 3.4e38f; mini[r] = 0; }

    for (int T = 0; T < 16; ++T) {
        __syncthreads();                 // buf[T&1] staged (vmcnt drained)
        if (T < 15) stage((T + 1) & 1, T + 1);
        const _Float16* bt = &btile[T & 1][0];
#pragma unroll
        for (int cc = 0; cc < 4; ++cc) {
            int k = cc * 16 + col;       // local code
            v8h bf[8];
#pragma unroll
            for (int c = 0; c < 8; ++c) {
                int g = c * 4 + quad;
                bf[c] = *(const v8h*)(bt + (size_t)k * D_DIM
                                      + ((g ^ ((k & 7) << 2)) << 3));
            }
            v4f acc0 = {0.f, 0.f, 0.f, 0.f};
            v4f acc1 = {0.f, 0.f, 0.f, 0.f};
#pragma unroll
            for (int c = 0; c < 8; ++c) {
                acc0 = __builtin_amdgcn_mfma_f32_16x16x32_f16(af0[c], bf[c], acc0, 0, 0, 0);
                acc1 = __builtin_amdgcn_mfma_f32_16x16x32_f16(af1[c], bf[c], acc1, 0, 0, 0);
            }
            int code = T * 64 + k;
            float n  = norm_s[code];
#pragma unroll
            for (int r = 0; r < 4; ++r) {
                float d0 = n - acc0[r];
                if (d0 < minv[r])     { minv[r]     = d0; mini[r]     = code; }
                float d1 = n - acc1[r];
                if (d1 < minv[4 + r]) { minv[4 + r] = d1; mini[4 + r] = code; }
            }
        }
    }
    // reduce across the 16 cols of each quad
#pragma unroll
    for (int off = 1; off < 16; off <<= 1) {
#pragma unroll
        for (int r = 0; r < 8; ++r) {
            float ov = __shfl_xor(minv[r], off);
            int   oi = __shfl_xor(mini[r], off);
            if (ov < minv[r] || (ov == minv[r] && oi < mini[r])) {
                minv[r] = ov; mini[r] = oi;
            }
        }
    }
    if (col == 0) {
#pragma unroll
        for (int r = 0; r < 8; ++r)
            idx_s[wave * 32 + (r >> 2) * 16 + quad * 4 + (r & 3)] = mini[r];
    }
    __syncthreads();

    // ---- epilogue: gather emb (L2-hot), write out, fused loss ----
    int hw4 = lane & 31;                 // fixed 4-row group per lane
    int code4[4];
#pragma unroll
    for (int j = 0; j < 4; ++j) code4[j] = idx_s[hw4 * 4 + j];
    float sum = 0.f;
#pragma unroll 4
    for (int i = 0; i < 32; ++i) {
        int d = i * 8 + wave * 2 + (lane >> 5);
        size_t base = (size_t)(b * D_DIM + d) * HW + hw0 + hw4 * 4;
        v4f e = *(const v4f*)(z + base);
        v4f q;
#pragma unroll
        for (int j = 0; j < 4; ++j)
            q[j] = emb[(size_t)code4[j] * D_DIM + d];
        v4f df = q - e;
        sum += df[0] * df[0] + df[1] * df[1] + df[2] * df[2] + df[3] * df[3];
        *(v4f*)(out + base) = q;         // z_q_st == z_q numerically
    }
    for (int off = 32; off; off >>= 1) sum += __shfl_down(sum, off);
    if (lane == 0) wred[wave] = sum;
    __syncthreads();
    if (t == 0) atomicAdd(loss_acc, wred[0] + wred[1] + wred[2] + wred[3]);
}

// ------------------------------------------------------------------
// K3: vq_loss = 1.25 * sum / TOT_ELEMS
__global__ void finalize(const float* __restrict__ loss_acc,
                         float* __restrict__ out_loss) {
    out_loss[0] = loss_acc[0] * (1.25f / (float)TOT_ELEMS);
}

// ------------------------------------------------------------------
extern "C" void kernel_launch(void* const* d_in, const int* in_sizes, int n_in,
                              void* d_out, int out_size, void* d_ws, size_t ws_size,
                              hipStream_t stream) {
    const float* z   = (const float*)d_in[0];   // [32,256,32,32]
    const float* emb = (const float*)d_in[1];   // [1024,256]
    float* out = (float*)d_out;                 // [8388608 z_q_st][1 loss]

    char* ws = (char*)d_ws;
    float*    loss_acc = (float*)ws;            // @0 (zeroed below)
    float*    hnorm    = (float*)(ws + 1024);   // 4 KB
    _Float16* emb_h    = (_Float16*)(ws + 8192);// 512 KB

    hipMemsetAsync(d_ws, 0, 256, stream);
    prep_emb<<<dim3(K_CODES), dim3(256), 0, stream>>>(emb, emb_h, hnorm);
    vq_main<<<dim3(256), dim3(256), 0, stream>>>(z, emb_h, emb, hnorm, out, loss_acc);
    finalize<<<dim3(1), dim3(1), 0, stream>>>(loss_acc, out + TOT_ELEMS);
}

// Round 4
// 123.676 us; speedup vs baseline: 1.8705x; 1.0967x over previous
//
#include <hip/hip_runtime.h>
#include <stdint.h>
#include <stddef.h>

// ---- problem constants ----
#define K_CODES 1024
#define D_DIM   256
#define HW      1024      // 32*32 spatial
#define N_VEC   32768
#define TOT_ELEMS 8388608

typedef float    v4f __attribute__((ext_vector_type(4)));
typedef _Float16 v8h __attribute__((ext_vector_type(8)));

// async global->LDS, 16B/lane, dest = wave-uniform base + lane*16
__device__ __forceinline__ void gld_lds16(const void* g, void* l) {
    __builtin_amdgcn_global_load_lds(
        (const __attribute__((address_space(1))) void*)g,
        (__attribute__((address_space(3))) void*)l, 16, 0, 0);
}

// ------------------------------------------------------------------
// K1: codebook -> fp16 copy + 0.5*||e||^2
__global__ void prep_emb(const float* __restrict__ emb,
                         _Float16* __restrict__ emb_h,
                         float* __restrict__ hnorm) {
    int k = blockIdx.x, t = threadIdx.x;
    float v = emb[(size_t)k * D_DIM + t];
    emb_h[(size_t)k * D_DIM + t] = (_Float16)v;
    float s = v * v;
    for (int off = 32; off; off >>= 1) s += __shfl_down(s, off);
    __shared__ float wsum[4];
    if ((t & 63) == 0) wsum[t >> 6] = s;
    __syncthreads();
    if (t == 0) hnorm[k] = 0.5f * (wsum[0] + wsum[1] + wsum[2] + wsum[3]);
}

// ------------------------------------------------------------------
// K2: fully fused VQ. 256 blocks x 512 thr (8 waves = 2/SIMD).
// Intra-block K-split x2: waves 0-3 scan codes 0-511, waves 4-7 codes
// 512-1023, same 128 rows; LDS merge. dist' = 0.5||e||^2 - <z,e>.
// Swizzle: granule g of code k stored at slot u = g ^ (k&7)
//   -> read bank-group = (g&7)^(col&7): 8 groups x2 per quarter (free).
__global__ __launch_bounds__(512, 2) void
vq_main(const float* __restrict__ z,
        const _Float16* __restrict__ emb_h,
        const float* __restrict__ emb,
        const float* __restrict__ hnorm,
        float* __restrict__ out,
        float* __restrict__ loss_acc) {
    __shared__ __align__(16) char smem[131072];   // btile[2grp][2buf][32KB] / zq
    __shared__ float  norm_s[K_CODES];
    __shared__ int    idx_s[128];
    __shared__ float2 mrg[4][32];
    __shared__ float  wred[8];

    _Float16* btile = (_Float16*)smem;

    int t    = threadIdx.x;
    int wave = t >> 6;
    int lane = t & 63;
    int grp  = wave >> 2;     // K-half
    int wv   = wave & 3;      // row-tile selector
    int col  = lane & 15;
    int quad = lane >> 4;
    int b    = blockIdx.x >> 3;
    int hw0  = (blockIdx.x & 7) * 128;
    const float* zb = z + (size_t)b * D_DIM * HW;

    // stage tile T (64 codes, 32 KB) of this wave's K-half
    auto stage = [&](int buf, int T) {
        const char* src = (const char*)(emb_h
                          + (size_t)(grp * 512 + T * 64) * D_DIM);
        char* dst = (char*)(btile + (size_t)(grp * 2 + buf) * 16384)
                    + wv * 8192;
#pragma unroll
        for (int i = 0; i < 8; ++i) {
            int k = wv * 16 + i * 2 + (lane >> 5);
            int g = (lane & 31) ^ (k & 7);
            gld_lds16(src + (size_t)k * 512 + (size_t)g * 16, dst + i * 1024);
        }
    };
    stage(0, 0);

    for (int i = t; i < K_CODES; i += 512) norm_s[i] = hnorm[i];

    // A fragments (32 rows/wave, both K-halves load same rows)
    int m0w = hw0 + wv * 32;
    v8h af0[8], af1[8];
#pragma unroll
    for (int c = 0; c < 8; ++c) {
#pragma unroll
        for (int j = 0; j < 8; ++j) {
            int d = c * 32 + quad * 8 + j;
            const float* p = zb + (size_t)d * HW + m0w + col;
            af0[c][j] = (_Float16)p[0];
            af1[c][j] = (_Float16)p[16];
        }
    }

    float minv[8]; int mini[8];
#pragma unroll
    for (int r = 0; r < 8; ++r) { minv[r] = 3.4e38f; mini[r] = 0; }

    for (int T = 0; T < 8; ++T) {
        __syncthreads();                 // staged buffer ready
        if (T < 7) stage((T + 1) & 1, T + 1);
        const _Float16* bt = btile + (size_t)(grp * 2 + (T & 1)) * 16384;
#pragma unroll
        for (int cc = 0; cc < 4; ++cc) {
            int k = cc * 16 + col;
            v8h bf[8];
#pragma unroll
            for (int c = 0; c < 8; ++c) {
                int u = (c * 4 + quad) ^ (col & 7);   // k&7 == col&7
                bf[c] = *(const v8h*)(bt + (size_t)k * D_DIM + (u << 3));
            }
            v4f acc0 = {0.f, 0.f, 0.f, 0.f};
            v4f acc1 = {0.f, 0.f, 0.f, 0.f};
#pragma unroll
            for (int c = 0; c < 8; ++c) {
                acc0 = __builtin_amdgcn_mfma_f32_16x16x32_f16(af0[c], bf[c], acc0, 0, 0, 0);
                acc1 = __builtin_amdgcn_mfma_f32_16x16x32_f16(af1[c], bf[c], acc1, 0, 0, 0);
            }
            int   code = grp * 512 + T * 64 + k;
            float n    = norm_s[code];
#pragma unroll
            for (int r = 0; r < 4; ++r) {
                float d0 = n - acc0[r];
                if (d0 < minv[r])     { minv[r]     = d0; mini[r]     = code; }
                float d1 = n - acc1[r];
                if (d1 < minv[4 + r]) { minv[4 + r] = d1; mini[4 + r] = code; }
            }
        }
    }
    // reduce across the 16 cols of each quad
#pragma unroll
    for (int off = 1; off < 16; off <<= 1) {
#pragma unroll
        for (int r = 0; r < 8; ++r) {
            float ov = __shfl_xor(minv[r], off);
            int   oi = __shfl_xor(mini[r], off);
            if (ov < minv[r] || (ov == minv[r] && oi < mini[r])) {
                minv[r] = ov; mini[r] = oi;
            }
        }
    }
    // K-split merge: half-1 posts, half-0 merges (strict < keeps low idx)
    if (grp == 1 && col == 0) {
#pragma unroll
        for (int r = 0; r < 8; ++r) {
            int rl = (r >> 2) * 16 + quad * 4 + (r & 3);
            mrg[wv][rl] = make_float2(minv[r], __int_as_float(mini[r]));
        }
    }
    __syncthreads();
    if (grp == 0 && col == 0) {
#pragma unroll
        for (int r = 0; r < 8; ++r) {
            int rl = (r >> 2) * 16 + quad * 4 + (r & 3);
            float2 m2 = mrg[wv][rl];
            int mi = mini[r];
            if (m2.x < minv[r]) mi = __float_as_int(m2.y);
            idx_s[wv * 32 + rl] = mi;
        }
    }
    __syncthreads();

    // ---- epilogue: gather emb rows -> LDS, write out + fused loss ----
    // group g handles rows hw0 + g*64 .. +63 in two 32-row passes
    float* zqg = (float*)smem + grp * 8224;   // 32 x 257 floats
    int tt = t & 255;
    float sum = 0.f;
    for (int s = 0; s < 2; ++s) {
        if (s) __syncthreads();
#pragma unroll 4
        for (int i = 0; i < 32; ++i)
            zqg[i * 257 + tt] =
                emb[(size_t)idx_s[grp * 64 + s * 32 + i] * D_DIM + tt];
        __syncthreads();
        int j = tt & 31, dq = tt >> 5;
#pragma unroll 4
        for (int p = 0; p < 32; ++p) {
            int d = dq * 32 + p;
            size_t o = (size_t)(b * D_DIM + d) * HW
                       + hw0 + grp * 64 + s * 32 + j;
            float q  = zqg[j * 257 + d];
            float e  = z[o];
            float df = q - e;
            sum += df * df;
            out[o] = q;                 // z_q_st == z_q numerically
        }
    }
    for (int off = 32; off; off >>= 1) sum += __shfl_down(sum, off);
    if (lane == 0) wred[wave] = sum;
    __syncthreads();
    if (t == 0) {
        float s8 = 0.f;
#pragma unroll
        for (int i = 0; i < 8; ++i) s8 += wred[i];
        atomicAdd(loss_acc, s8);
    }
}

// ------------------------------------------------------------------
// K3: vq_loss = 1.25 * sum / TOT_ELEMS
__global__ void finalize(const float* __restrict__ loss_acc,
                         float* __restrict__ out_loss) {
    out_loss[0] = loss_acc[0] * (1.25f / (float)TOT_ELEMS);
}

// ------------------------------------------------------------------
extern "C" void kernel_launch(void* const* d_in, const int* in_sizes, int n_in,
                              void* d_out, int out_size, void* d_ws, size_t ws_size,
                              hipStream_t stream) {
    const float* z   = (const float*)d_in[0];   // [32,256,32,32]
    const float* emb = (const float*)d_in[1];   // [1024,256]
    float* out = (float*)d_out;                 // [8388608 z_q_st][1 loss]

    char* ws = (char*)d_ws;
    float*    loss_acc = (float*)ws;            // @0 (zeroed below)
    float*    hnorm    = (float*)(ws + 1024);   // 4 KB
    _Float16* emb_h    = (_Float16*)(ws + 8192);// 512 KB

    hipMemsetAsync(d_ws, 0, 256, stream);
    prep_emb<<<dim3(K_CODES), dim3(256), 0, stream>>>(emb, emb_h, hnorm);
    vq_main<<<dim3(256), dim3(512), 0, stream>>>(z, emb_h, emb, hnorm, out, loss_acc);
    finalize<<<dim3(1), dim3(1), 0, stream>>>(loss_acc, out + TOT_ELEMS);
}